// Round 2
// baseline (389.801 us; speedup 1.0000x reference)
//
#include <hip/hip_runtime.h>

// SpectralLayer reduction (algebra verified; fp32 buffers confirmed round 4):
//   out[:, :512]  = data[:, :512]                        (exact pass-through)
//   out[:, 512+n] = relu( d_n*data[:,512+n] + (1-d_n)*t_n ),
//       t = data[:, :512] @ W^T,  W[n][k] = base[512+n][k],  d = v^2 - v + 1
// Round 7: BARRIER-FREE k-loop. Rounds 5/6 proved the per-iteration
// __syncthreads vmcnt(0) drain is the bottleneck (conflicts->0, prefetch,
// FETCH -16%: time unchanged, all pipes idle). New structure:
//   - W panel (64 cols x 512 k, bf16, XOR-swizzled) staged into LDS ONCE
//     per block (one barrier in the whole kernel). 64 KB -> 2 blocks/CU.
//   - A streamed global->regs in fragment order, fp32->bf16 packed in-reg,
//     2-deep register pipeline, NO ds_write/barriers in the k-loop. Loads
//     are never force-drained; compiler pipelines freely.
//   - A redundancy (x2 waves, x8 col-blocks) is L3-absorbed (first half of
//     data = 64 MB < 256 MB L3; same-x blocks share an XCD: id%8 == x%8).

typedef float f32x4 __attribute__((ext_vector_type(4)));
typedef int   i32x4 __attribute__((ext_vector_type(4)));
typedef unsigned int u32x4 __attribute__((ext_vector_type(4)));

#define DIMW   1024
#define HALFD  512
#define BM     128
#define BN     64
#define NITER  16          // K = 512, BK = 32

__device__ __forceinline__ unsigned short f2bf(float x) {
    union { float f; unsigned int i; } c;
    c.f = x;
    unsigned int r = c.i + 0x7FFFu + ((c.i >> 16) & 1u);  // round-nearest-even
    return (unsigned short)(r >> 16);
}
__device__ __forceinline__ unsigned int pack2(float a, float b) {
    return (unsigned int)f2bf(a) | ((unsigned int)f2bf(b) << 16);
}

// D(f32x4) += A(8 bf16 in 4 VGPRs) * B(8 bf16 in 4 VGPRs); C tied to D.
__device__ __forceinline__ void mfma_16x16x32_bf16(f32x4& d, const i32x4& a, const i32x4& b) {
    asm volatile("v_mfma_f32_16x16x32_bf16 %0, %1, %2, %0"
                 : "+v"(d)
                 : "v"(a), "v"(b));
}
// Hazard fence: VALU may not read an MFMA result for ~8 cycles.
__device__ __forceinline__ void acc_fence(f32x4& d) {
    asm volatile("s_nop 7\n\ts_nop 7" : "+v"(d));
}

// LDS swizzle for Bs[col][k] (bf16, k-contiguous rows of 1024 B):
//   byte ^= ((col&7) ^ ((k>>7)&3)) << 4
// 16B-granular (preserves ds_read_b128 / uint4-write alignment); spreads the
// 16-lane same-bank read (stride 1024 B) and the staging-write pattern to
// <=2-way (free, m136). Bijective: XOR of addr bits 4-6 by a function of
// disjoint higher addr bits.
__device__ __forceinline__ int bs_addr(int col, int k) {
    return (col * 1024 + k * 2) ^ ((((col & 7) ^ ((k >> 7) & 3))) << 4);
}

__global__ __launch_bounds__(256, 2) void spectral_kernel(
    const float* __restrict__ data,
    const float* __restrict__ wsrc,   // base: W at rows [512,1024), cols [0,512)
    const float* __restrict__ td,
    const float* __restrict__ tdm,
    const float* __restrict__ ud,
    float* __restrict__ out)
{
    __shared__ unsigned short Bs[BN * HALFD];   // 64 cols x 512 k bf16 = 64 KB

    const int tid    = (int)threadIdx.x;
    const int lane   = tid & 63;
    const int wave   = tid >> 6;
    const int lane16 = lane & 15;
    const int quad   = lane >> 4;
    const int wm     = wave >> 1;            // 2x2 wave grid; wave tile 64m x 32n
    const int wn     = wave & 1;
    const int rowBase = (int)blockIdx.x * BM;
    const int colBase = (int)blockIdx.y * BN;   // n in [0,512)

    // ---- Stage W once: Bs[col][k] = bf16(W[colBase+col][k]) ----
    {
        const int cw = tid >> 2;              // col 0..63
        const int ks = (tid & 3) * 128;       // k segment base
        const float* wr = wsrc + (size_t)(HALFD + colBase + cw) * DIMW + ks;
        #pragma unroll
        for (int g = 0; g < 16; ++g) {
            const int k = ks + g * 8;
            float4 f0 = *(const float4*)(wr + g * 8);
            float4 f1 = *(const float4*)(wr + g * 8 + 4);
            u32x4 u;
            u[0] = pack2(f0.x, f0.y);  u[1] = pack2(f0.z, f0.w);
            u[2] = pack2(f1.x, f1.y);  u[3] = pack2(f1.z, f1.w);
            *(u32x4*)((char*)Bs + bs_addr(cw, k)) = u;
        }
    }
    __syncthreads();    // the ONLY barrier in the kernel

    f32x4 acc[4][2];
    #pragma unroll
    for (int mi = 0; mi < 4; ++mi)
        #pragma unroll
        for (int ni = 0; ni < 2; ++ni)
            acc[mi][ni] = (f32x4){0.f, 0.f, 0.f, 0.f};

    // A fragment loads: lane (lane16, quad) of wave wm needs, per mi,
    // data[rowBase + wm*64 + mi*16 + lane16][k0 + quad*8 .. +8]  (8 fp32 = 32 B).
    // Lanes {l, l+16, l+32, l+48} cover 128 B contiguous per row -> coalesced.
    const float* abase = data + (size_t)(rowBase + wm * 64 + lane16) * DIMW + quad * 8;

    float4 x0[4], x1[4], y0[4], y1[4];   // 2-deep register pipeline (named sets,
                                          // static indexing only — rule #20)
    auto LDA = [&](int k0, float4 (&q0)[4], float4 (&q1)[4]) {
        #pragma unroll
        for (int mi = 0; mi < 4; ++mi) {
            const float* p = abase + (size_t)(mi * 16) * DIMW + k0;
            q0[mi] = *(const float4*)p;
            q1[mi] = *(const float4*)(p + 4);
        }
    };
    auto STEP = [&](int it, float4 (&q0)[4], float4 (&q1)[4]) {
        i32x4 a[4];
        #pragma unroll
        for (int mi = 0; mi < 4; ++mi) {
            i32x4 t;
            t[0] = (int)pack2(q0[mi].x, q0[mi].y);
            t[1] = (int)pack2(q0[mi].z, q0[mi].w);
            t[2] = (int)pack2(q1[mi].x, q1[mi].y);
            t[3] = (int)pack2(q1[mi].z, q1[mi].w);
            a[mi] = t;
        }
        i32x4 b[2];
        #pragma unroll
        for (int ni = 0; ni < 2; ++ni) {
            const int col = wn * 32 + ni * 16 + lane16;
            b[ni] = *(const i32x4*)((const char*)Bs + bs_addr(col, it * 32 + quad * 8));
        }
        #pragma unroll
        for (int mi = 0; mi < 4; ++mi)
            #pragma unroll
            for (int ni = 0; ni < 2; ++ni)
                mfma_16x16x32_bf16(acc[mi][ni], a[mi], b[ni]);
    };

    LDA(0, x0, x1);
    #pragma unroll
    for (int it = 0; it < NITER; it += 2) {
        LDA((it + 1) * 32, y0, y1);              // prefetch next
        STEP(it, x0, x1);
        if (it + 2 < NITER) LDA((it + 2) * 32, x0, x1);   // prefetch next+1
        STEP(it + 1, y0, y1);
    }

    #pragma unroll
    for (int mi = 0; mi < 4; ++mi)
        #pragma unroll
        for (int ni = 0; ni < 2; ++ni)
            acc_fence(acc[mi][ni]);

    // Epilogue. C/D layout: col(n) = lane&15, row(m) = quad*4 + reg. [m89 verified]
    // d_n read directly from the diag arrays (16-lane-shared dwords, L1/L2 hit).
    #pragma unroll
    for (int ni = 0; ni < 2; ++ni) {
        const int nloc = wn * 32 + ni * 16 + lane16;
        const int j  = HALFD + colBase + nloc;
        const size_t fi = (size_t)j * DIMW + j;
        const float dv = td[fi] * tdm[fi] + ud[fi];
        #pragma unroll
        for (int mi = 0; mi < 4; ++mi) {
            const int mBase = rowBase + wm * 64 + mi * 16 + quad * 4;
            #pragma unroll
            for (int r = 0; r < 4; ++r) {
                const size_t gi = (size_t)(mBase + r) * DIMW + j;
                const float u1 = data[gi];
                const float v  = dv * u1 + (1.0f - dv) * acc[mi][ni][r];
                out[gi] = fmaxf(v, 0.0f);
            }
        }
    }

    // Fused pass-through copy: out[rowBase..+128, colBase..+64) = data[same].
    {
        const float4* src = (const float4*)data;   // 256 float4 per row
        float4*       dst = (float4*)out;
        #pragma unroll
        for (int p = 0; p < 8; ++p) {
            int c  = p * 256 + tid;                // 2048 chunks: 128 rows x 16
            int r  = c >> 4;
            int cc = c & 15;
            size_t off = (size_t)(rowBase + r) * (DIMW / 4) + (colBase >> 2) + cc;
            dst[off] = src[off];
        }
    }
}

extern "C" void kernel_launch(void* const* d_in, const int* in_sizes, int n_in,
                              void* d_out, int out_size, void* d_ws, size_t ws_size,
                              hipStream_t stream) {
    // setup_inputs order: 0 data, 1 base, 2 base_mask, 3 eye, 4 trainable_diag,
    //                     5 trainable_diag_mask, 6 untrainable_diag, 7 mask1, 8 mask2
    const float* data = (const float*)d_in[0];
    const float* base = (const float*)d_in[1];
    const float* td   = (const float*)d_in[4];
    const float* tdm  = (const float*)d_in[5];
    const float* ud   = (const float*)d_in[6];
    float* out = (float*)d_out;

    dim3 grid(32768 / BM, HALFD / BN);   // 256 x 8 = 2048 blocks
    dim3 block(256, 1, 1);
    spectral_kernel<<<grid, block, 0, stream>>>(data, base, td, tdm, ud, out);
}

// Round 4
// 367.391 us; speedup vs baseline: 1.0610x; 1.0610x over previous
//
#include <hip/hip_runtime.h>

// SpectralLayer reduction (algebra verified; fp32 buffers confirmed):
//   out[:, :512]  = data[:, :512]                        (exact pass-through)
//   out[:, 512+n] = relu( d_n*data[:,512+n] + (1-d_n)*t_n ),
//       t = data[:, :512] @ W^T,  W[n][k] = base[512+n][k],  d = v^2 - v + 1
// Round 9: round-8 architecture (zero-redundancy A, barrier-free k-loop)
// rebuilt from ONLY harness-verified components after r8's correctness fail:
//   - pack2/f2bf (rounds 0-6 verified) instead of v_cvt_pk asm
//   - padded-linear A-LDS [64][520] (2-way banks = free) instead of XOR swizzle
//   - W fragments loaded fp32 from wsrc + packed in-register (r5/r6-verbatim
//     pattern; W is 1 MB -> L2-resident) instead of the wprep workspace table
//   - diag read directly in epilogue (r7-verified), no dsh
// Structure: block = 64 rows x ALL 512 cols (512 blocks = 2/CU), A staged once
// into LDS fused with the out[:, :512] pass-through (A read from HBM exactly
// once), ONE barrier total, 1-deep W prefetch, no vmcnt(0) drains in the loop.

typedef float f32x4 __attribute__((ext_vector_type(4)));
typedef int   i32x4 __attribute__((ext_vector_type(4)));

#define DIMW   1024
#define HALFD  512
#define BM     64
#define LDAP   520         // padded LDS row stride (elements); 1040 B = 65*16
#define NITER  16          // K = 512, BK = 32

__device__ __forceinline__ unsigned short f2bf(float x) {
    union { float f; unsigned int i; } c;
    c.f = x;
    unsigned int r = c.i + 0x7FFFu + ((c.i >> 16) & 1u);  // round-nearest-even
    return (unsigned short)(r >> 16);
}
__device__ __forceinline__ unsigned int pack2(float a, float b) {
    return (unsigned int)f2bf(a) | ((unsigned int)f2bf(b) << 16);
}

// D(f32x4) += A(8 bf16 in 4 VGPRs) * B(8 bf16 in 4 VGPRs); C tied to D.
__device__ __forceinline__ void mfma_16x16x32_bf16(f32x4& d, const i32x4& a, const i32x4& b) {
    asm volatile("v_mfma_f32_16x16x32_bf16 %0, %1, %2, %0"
                 : "+v"(d)
                 : "v"(a), "v"(b));
}
// Hazard fence: VALU may not read an MFMA result for ~8 cycles.
__device__ __forceinline__ void acc_fence(f32x4& d) {
    asm volatile("s_nop 7\n\ts_nop 7" : "+v"(d));
}

__global__ __launch_bounds__(512, 4) void spectral_kernel(
    const float* __restrict__ data,
    const float* __restrict__ wsrc,   // base: W at rows [512,1024), cols [0,512)
    const float* __restrict__ td,
    const float* __restrict__ tdm,
    const float* __restrict__ ud,
    float* __restrict__ out)
{
    // A tile: 64 rows x 512 k, bf16, padded row stride 520 elem (1040 B).
    // ds_read_b128 frag reads: lanes 0..15 start at bank 4*l mod 32 -> 2
    // lanes/bank (free, m136). 66560 B -> 2 blocks/CU.
    __shared__ unsigned short As[BM * LDAP];

    const int tid    = (int)threadIdx.x;
    const int lane   = tid & 63;
    const int wn     = tid >> 6;               // wave 0..7 -> col panel wn*64
    const int lane16 = lane & 15;
    const int quad   = lane >> 4;
    const int rowBase = (int)blockIdx.x * BM;

    // ---- Stage A once (bf16) + fused pass-through out[:, :512] ----
    // 64 rows x 128 float4 chunks; 16 per thread; contiguous per wave.
    #pragma unroll
    for (int p = 0; p < 16; ++p) {
        int c  = p * 512 + tid;
        int r  = c >> 7;
        int cc = c & 127;
        size_t off = (size_t)(rowBase + r) * DIMW + cc * 4;
        float4 v = *(const float4*)(data + off);
        *(float4*)(out + off) = v;                     // pass-through
        uint2 uu;
        uu.x = pack2(v.x, v.y);
        uu.y = pack2(v.z, v.w);
        *(uint2*)(As + r * LDAP + cc * 4) = uu;        // byte 1040r + 8cc
    }

    i32x4 b0[4], b1[4];  // 1-deep W prefetch (named sets, static indexing)

    // W fragment: lane holds W[col = wn*64 + ni*16 + lane16][k .. k+7],
    // loaded fp32 (two float4) + packed in-register. L2-resident (1 MB).
    auto LDW = [&](int it, i32x4 (&b)[4]) {
        #pragma unroll
        for (int ni = 0; ni < 4; ++ni) {
            int col = wn * 64 + ni * 16 + lane16;
            const float* p = wsrc + (size_t)(HALFD + col) * DIMW + it * 32 + quad * 8;
            float4 f0 = *(const float4*)p;
            float4 f1 = *(const float4*)(p + 4);
            i32x4 t;
            t[0] = (int)pack2(f0.x, f0.y);  t[1] = (int)pack2(f0.z, f0.w);
            t[2] = (int)pack2(f1.x, f1.y);  t[3] = (int)pack2(f1.z, f1.w);
            b[ni] = t;
        }
    };

    // Issue the first two W tiles before the barrier (overlap with LDS drain).
    LDW(0, b0);
    LDW(1, b1);
    __syncthreads();    // the ONLY barrier in the kernel

    f32x4 acc[4][4];    // wave tile 64m x 64n: 16 fragments
    #pragma unroll
    for (int mi = 0; mi < 4; ++mi)
        #pragma unroll
        for (int ni = 0; ni < 4; ++ni)
            acc[mi][ni] = (f32x4){0.f, 0.f, 0.f, 0.f};

    auto STEP = [&](int it, i32x4 (&b)[4]) {
        i32x4 a[4];
        #pragma unroll
        for (int mi = 0; mi < 4; ++mi)
            a[mi] = *(const i32x4*)(As + (mi * 16 + lane16) * LDAP + it * 32 + quad * 8);
        #pragma unroll
        for (int mi = 0; mi < 4; ++mi)
            #pragma unroll
            for (int ni = 0; ni < 4; ++ni)
                mfma_16x16x32_bf16(acc[mi][ni], a[mi], b[ni]);
    };

    #pragma unroll
    for (int it = 0; it < NITER; it += 2) {
        STEP(it, b0);
        if (it + 2 < NITER) LDW(it + 2, b0);
        STEP(it + 1, b1);
        if (it + 3 < NITER) LDW(it + 3, b1);
    }

    #pragma unroll
    for (int mi = 0; mi < 4; ++mi)
        #pragma unroll
        for (int ni = 0; ni < 4; ++ni)
            acc_fence(acc[mi][ni]);

    // Epilogue. C/D layout: col(n) = lane&15, row(m) = quad*4 + reg. [m89]
    // d_n read directly from diag arrays (16-lane-shared dwords, cache hits).
    #pragma unroll
    for (int ni = 0; ni < 4; ++ni) {
        const int nloc = wn * 64 + ni * 16 + lane16;
        const int j  = HALFD + nloc;
        const size_t fi = (size_t)j * DIMW + j;
        const float dv = td[fi] * tdm[fi] + ud[fi];
        #pragma unroll
        for (int mi = 0; mi < 4; ++mi) {
            const int mBase = rowBase + mi * 16 + quad * 4;
            #pragma unroll
            for (int r = 0; r < 4; ++r) {
                const size_t gi = (size_t)(mBase + r) * DIMW + j;
                const float u1 = data[gi];
                const float v  = dv * u1 + (1.0f - dv) * acc[mi][ni][r];
                out[gi] = fmaxf(v, 0.0f);
            }
        }
    }
}

extern "C" void kernel_launch(void* const* d_in, const int* in_sizes, int n_in,
                              void* d_out, int out_size, void* d_ws, size_t ws_size,
                              hipStream_t stream) {
    // setup_inputs order: 0 data, 1 base, 2 base_mask, 3 eye, 4 trainable_diag,
    //                     5 trainable_diag_mask, 6 untrainable_diag, 7 mask1, 8 mask2
    const float* data = (const float*)d_in[0];
    const float* base = (const float*)d_in[1];
    const float* td   = (const float*)d_in[4];
    const float* tdm  = (const float*)d_in[5];
    const float* ud   = (const float*)d_in[6];
    float* out = (float*)d_out;

    dim3 block(512, 1, 1);
    dim3 grid(32768 / BM, 1, 1);               // 512 blocks = 2 per CU
    spectral_kernel<<<grid, block, 0, stream>>>(data, base, td, tdm, ud, out);
}

// Round 5
// 346.780 us; speedup vs baseline: 1.1241x; 1.0594x over previous
//
#include <hip/hip_runtime.h>

// SpectralLayer reduction (algebra verified; fp32 buffers confirmed):
//   out[:, :512]  = data[:, :512]                        (exact pass-through)
//   out[:, 512+n] = relu( d_n*data[:,512+n] + (1-d_n)*t_n ),
//       t = data[:, :512] @ W^T,  W[n][k] = base[512+n][k],  d = v^2 - v + 1
// Round 10: latency-exposure fixes on the r9 zero-redundancy skeleton.
//   (1) MFMA operand swap: mfma(acc, b, a) -> output lane16 = data-row,
//       quad*4+reg = 4 CONSECUTIVE W-cols => epilogue is float4 loads/stores
//       (16 vector mem-ops/thread vs 128 scalar). No fragment-load changes.
//   (2) Pass-through copy split into 256 dedicated copy blocks (0 LDS, low
//       VGPR) dispatched FIRST: co-resident pure-streaming waves keep HBM
//       busy while GEMM waves sit in the L2-only k-loop; also warms L3 so
//       the GEMM prologue's lower-half read is L3-absorbed.
//   (3) GEMM prologue: no out-store, loads in 8-deep float4 batches.
// r9 measured: 171 us, 240 MB (ideal), 1.4 TB/s, 4.5x latency exposure.

typedef float f32x4 __attribute__((ext_vector_type(4)));
typedef int   i32x4 __attribute__((ext_vector_type(4)));

#define DIMW   1024
#define HALFD  512
#define BM     64
#define LDAP   520         // padded LDS row stride (elements); 1040 B = 65*16
#define NITER  16          // K = 512, BK = 32
#define NCOPY  256         // dedicated pass-through copy blocks (128 rows each)

__device__ __forceinline__ unsigned short f2bf(float x) {
    union { float f; unsigned int i; } c;
    c.f = x;
    unsigned int r = c.i + 0x7FFFu + ((c.i >> 16) & 1u);  // round-nearest-even
    return (unsigned short)(r >> 16);
}
__device__ __forceinline__ unsigned int pack2(float a, float b) {
    return (unsigned int)f2bf(a) | ((unsigned int)f2bf(b) << 16);
}

// D(f32x4) += A(8 bf16 in 4 VGPRs) * B(8 bf16 in 4 VGPRs); C tied to D.
__device__ __forceinline__ void mfma_16x16x32_bf16(f32x4& d, const i32x4& a, const i32x4& b) {
    asm volatile("v_mfma_f32_16x16x32_bf16 %0, %1, %2, %0"
                 : "+v"(d)
                 : "v"(a), "v"(b));
}
// Hazard fence: VALU may not read an MFMA result for ~8 cycles.
__device__ __forceinline__ void acc_fence(f32x4& d) {
    asm volatile("s_nop 7\n\ts_nop 7" : "+v"(d));
}

__global__ __launch_bounds__(512, 4) void spectral_kernel(
    const float* __restrict__ data,
    const float* __restrict__ wsrc,   // base: W at rows [512,1024), cols [0,512)
    const float* __restrict__ td,
    const float* __restrict__ tdm,
    const float* __restrict__ ud,
    float* __restrict__ out)
{
    const int tid = (int)threadIdx.x;

    // ---------------- copy blocks: out[:, :512] = data[:, :512] -------------
    if ((int)blockIdx.x < NCOPY) {
        const int rowBase = (int)blockIdx.x * 128;
        const float4* src = (const float4*)data;
        float4*       dst = (float4*)out;
        // 128 rows x 128 float4 = 16384 chunks; 32/thread in 8-deep batches.
        #pragma unroll
        for (int h = 0; h < 4; ++h) {
            float4 v[8];
            #pragma unroll
            for (int p = 0; p < 8; ++p) {
                int c  = (h * 8 + p) * 512 + tid;
                int r  = c >> 7;
                int cc = c & 127;
                v[p] = src[(size_t)(rowBase + r) * (DIMW / 4) + cc];
            }
            #pragma unroll
            for (int p = 0; p < 8; ++p) {
                int c  = (h * 8 + p) * 512 + tid;
                int r  = c >> 7;
                int cc = c & 127;
                dst[(size_t)(rowBase + r) * (DIMW / 4) + cc] = v[p];
            }
        }
        return;
    }

    // ---------------- GEMM blocks: 64 rows x all 512 cols -------------------
    __shared__ unsigned short As[BM * LDAP];   // 66,560 B
    __shared__ float dsh[HALFD];               //  2,048 B

    const int lane   = tid & 63;
    const int wn     = tid >> 6;               // wave 0..7 -> col panel wn*64
    const int lane16 = lane & 15;
    const int quad   = lane >> 4;
    const int rowBase = ((int)blockIdx.x - NCOPY) * BM;

    // d[n] for all 512 output cols (diag entries at [512+n][512+n])
    {
        int j = HALFD + tid;
        size_t fi = (size_t)j * DIMW + j;
        dsh[tid] = td[fi] * tdm[fi] + ud[fi];
    }

    // ---- Stage A once (bf16, padded-linear) : 8-deep load batches ----
    #pragma unroll
    for (int h = 0; h < 2; ++h) {
        float4 v[8];
        #pragma unroll
        for (int p = 0; p < 8; ++p) {
            int c  = (h * 8 + p) * 512 + tid;
            int r  = c >> 7;
            int cc = c & 127;
            v[p] = *(const float4*)(data + (size_t)(rowBase + r) * DIMW + cc * 4);
        }
        #pragma unroll
        for (int p = 0; p < 8; ++p) {
            int c  = (h * 8 + p) * 512 + tid;
            int r  = c >> 7;
            int cc = c & 127;
            uint2 uu;
            uu.x = pack2(v[p].x, v[p].y);
            uu.y = pack2(v[p].z, v[p].w);
            *(uint2*)(As + r * LDAP + cc * 4) = uu;
        }
    }

    i32x4 b0[4], b1[4];  // 1-deep W prefetch (named sets, static indexing)

    // W fragment: lane holds W[col = wn*64 + ni*16 + lane16][k .. k+7],
    // loaded fp32 (two float4) + packed in-register. L2-resident (1 MB).
    auto LDW = [&](int it, i32x4 (&b)[4]) {
        #pragma unroll
        for (int ni = 0; ni < 4; ++ni) {
            int col = wn * 64 + ni * 16 + lane16;
            const float* p = wsrc + (size_t)(HALFD + col) * DIMW + it * 32 + quad * 8;
            float4 f0 = *(const float4*)p;
            float4 f1 = *(const float4*)(p + 4);
            i32x4 t;
            t[0] = (int)pack2(f0.x, f0.y);  t[1] = (int)pack2(f0.z, f0.w);
            t[2] = (int)pack2(f1.x, f1.y);  t[3] = (int)pack2(f1.z, f1.w);
            b[ni] = t;
        }
    };

    LDW(0, b0);
    LDW(1, b1);
    __syncthreads();    // the ONLY barrier in the kernel

    f32x4 acc[4][4];    // acc[mi][ni]: data-rows mi*16+lane16, w-cols ni*16+quad*4+r
    #pragma unroll
    for (int mi = 0; mi < 4; ++mi)
        #pragma unroll
        for (int ni = 0; ni < 4; ++ni)
            acc[mi][ni] = (f32x4){0.f, 0.f, 0.f, 0.f};

    // SWAPPED operands: mfma(acc, W-frag, data-frag).
    // D-row axis (quad*4+reg) <- A-operand (W) lane16 axis = w-col;
    // D-col axis (lane16)     <- B-operand (data) lane16 axis = data-row.
    auto STEP = [&](int it, i32x4 (&b)[4]) {
        i32x4 a[4];
        #pragma unroll
        for (int mi = 0; mi < 4; ++mi)
            a[mi] = *(const i32x4*)(As + (mi * 16 + lane16) * LDAP + it * 32 + quad * 8);
        #pragma unroll
        for (int mi = 0; mi < 4; ++mi)
            #pragma unroll
            for (int ni = 0; ni < 4; ++ni)
                mfma_16x16x32_bf16(acc[mi][ni], b[ni], a[mi]);
    };

    #pragma unroll
    for (int it = 0; it < NITER; it += 2) {
        STEP(it, b0);
        if (it + 2 < NITER) LDW(it + 2, b0);
        STEP(it + 1, b1);
        if (it + 3 < NITER) LDW(it + 3, b1);
    }

    #pragma unroll
    for (int mi = 0; mi < 4; ++mi)
        #pragma unroll
        for (int ni = 0; ni < 4; ++ni)
            acc_fence(acc[mi][ni]);

    // Epilogue (vectorized): per (mi,ni) lane handles row = rowBase+mi*16+lane16,
    // cols 512 + wn*64 + ni*16 + quad*4 .. +4  -> float4 load/compute/store.
    #pragma unroll
    for (int mi = 0; mi < 4; ++mi) {
        const int row = rowBase + mi * 16 + lane16;
        const float* drow = data + (size_t)row * DIMW + HALFD;
        float*       orow = out  + (size_t)row * DIMW + HALFD;
        #pragma unroll
        for (int ni = 0; ni < 4; ++ni) {
            const int colb = wn * 64 + ni * 16 + quad * 4;
            float4 u1 = *(const float4*)(drow + colb);
            float4 d4 = *(const float4*)(dsh + colb);
            float4 o;
            o.x = fmaxf(d4.x * u1.x + (1.0f - d4.x) * acc[mi][ni][0], 0.0f);
            o.y = fmaxf(d4.y * u1.y + (1.0f - d4.y) * acc[mi][ni][1], 0.0f);
            o.z = fmaxf(d4.z * u1.z + (1.0f - d4.z) * acc[mi][ni][2], 0.0f);
            o.w = fmaxf(d4.w * u1.w + (1.0f - d4.w) * acc[mi][ni][3], 0.0f);
            *(float4*)(orow + colb) = o;
        }
    }
}

extern "C" void kernel_launch(void* const* d_in, const int* in_sizes, int n_in,
                              void* d_out, int out_size, void* d_ws, size_t ws_size,
                              hipStream_t stream) {
    // setup_inputs order: 0 data, 1 base, 2 base_mask, 3 eye, 4 trainable_diag,
    //                     5 trainable_diag_mask, 6 untrainable_diag, 7 mask1, 8 mask2
    const float* data = (const float*)d_in[0];
    const float* base = (const float*)d_in[1];
    const float* td   = (const float*)d_in[4];
    const float* tdm  = (const float*)d_in[5];
    const float* ud   = (const float*)d_in[6];
    float* out = (float*)d_out;

    dim3 block(512, 1, 1);
    dim3 grid(NCOPY + 32768 / BM, 1, 1);       // 256 copy + 512 GEMM blocks
    spectral_kernel<<<grid, block, 0, stream>>>(data, base, td, tdm, ud, out);
}